// Round 3
// baseline (740.117 us; speedup 1.0000x reference)
//
#include <hip/hip_runtime.h>
#include <math.h>

// ---------------- constants ----------------
#define EMB   1024
#define NH    16
#define HD    64
#define BATCH 4
#define LSEQ  1024
#define NTOK  (BATCH*LSEQ)          // 4096
#define SCALING 0.39528470752104744f // (64*0.1)^-0.5

typedef __attribute__((ext_vector_type(8))) short short8;   // 8 bf16 = 4 VGPRs
typedef __attribute__((ext_vector_type(4))) float f32x4;

__device__ __forceinline__ float bf2f(short s) {
    union { float f; unsigned u; } x; x.u = ((unsigned)(unsigned short)s) << 16; return x.f;
}
__device__ __forceinline__ short f2bf(float f) {
    union { float f; unsigned u; } x; x.f = f;
    unsigned r = x.u + 0x7fff + ((x.u >> 16) & 1);
    return (short)(r >> 16);
}

__device__ __forceinline__ void glds16(const void* g, void* l) {
    __builtin_amdgcn_global_load_lds(
        (const __attribute__((address_space(1))) void*)g,
        (__attribute__((address_space(3))) void*)l, 16, 0, 0);
}

// ================= Kernel 0: f32 -> bf16 conversion =================
__global__ __launch_bounds__(256) void cvt_bf16(
    const float* __restrict__ in, short* __restrict__ out, int n)
{
    int i = (blockIdx.x * 256 + threadIdx.x) * 8;
    if (i >= n) return;
    float4 a = *(const float4*)(in + i);
    float4 b = *(const float4*)(in + i + 4);
    short8 o;
    o[0] = f2bf(a.x); o[1] = f2bf(a.y); o[2] = f2bf(a.z); o[3] = f2bf(a.w);
    o[4] = f2bf(b.x); o[5] = f2bf(b.y); o[6] = f2bf(b.z); o[7] = f2bf(b.w);
    *(short8*)(out + i) = o;
}

// ================= Kernel 1: QKV GEMM =================
// qkv[n][f] = sum_e X[n][e]*Wqkv[f][e] + bqkv[f].
// Q,K scatter to [bh][l][d]; V scatters TRANSPOSED to [bh][d][l] so the
// attention kernel needs no LDS transpose.
__global__ __launch_bounds__(256) void qkv_gemm(
    const short* __restrict__ X, const short* __restrict__ W,
    const float* __restrict__ bqkv,
    short* __restrict__ qws, short* __restrict__ kws, short* __restrict__ vws)
{
    __shared__ short As[128 * 32];
    __shared__ short Bs[128 * 32];
    const int tid = threadIdx.x;
    const int wave = tid >> 6, lane = tid & 63;
    const int quad = lane >> 4, l16 = lane & 15;
    const int m0 = blockIdx.y * 128, n0 = blockIdx.x * 128;
    const int wm = (wave >> 1) * 64, wn = (wave & 1) * 64;

    f32x4 acc[4][4] = {};

    const int srow = wave * 16 + (lane >> 2);
    const int scol = (lane & 3) * 16;
    const char* gA = (const char*)X + (size_t)(m0 + srow) * 2048 + scol;
    const char* gB = (const char*)W + (size_t)(n0 + srow) * 2048 + scol;
    char* lA = (char*)As + wave * 1024 + lane * 16;
    char* lB = (char*)Bs + wave * 1024 + lane * 16;

    for (int kt = 0; kt < 1024; kt += 32) {
        __syncthreads();
        const char* ga = gA + kt * 2;
        const char* gb = gB + kt * 2;
        glds16(ga, lA);
        glds16(ga + (size_t)64 * 2048, lA + 4096);
        glds16(gb, lB);
        glds16(gb + (size_t)64 * 2048, lB + 4096);
        __syncthreads();

        short8 af[4], bf[4];
        #pragma unroll
        for (int i = 0; i < 4; i++)
            af[i] = *(const short8*)((const char*)As + (wm + i * 16 + l16) * 64 + quad * 16);
        #pragma unroll
        for (int j = 0; j < 4; j++)
            bf[j] = *(const short8*)((const char*)Bs + (wn + j * 16 + l16) * 64 + quad * 16);
        #pragma unroll
        for (int i = 0; i < 4; i++)
            #pragma unroll
            for (int j = 0; j < 4; j++)
                acc[i][j] = __builtin_amdgcn_mfma_f32_16x16x32_bf16(af[i], bf[j], acc[i][j], 0, 0, 0);
    }

    #pragma unroll
    for (int i = 0; i < 4; i++) {
        #pragma unroll
        for (int j = 0; j < 4; j++) {
            #pragma unroll
            for (int r = 0; r < 4; r++) {
                int gm = m0 + wm + i * 16 + quad * 4 + r;   // token index
                int gn = n0 + wn + j * 16 + l16;            // feature in [0,3072)
                float v = acc[i][j][r] + bqkv[gn];
                int part = gn >> 10;
                int cc = gn & 1023;
                int h = cc >> 6, d = cc & 63;
                int b = gm >> 10, l = gm & 1023;
                size_t bh = (size_t)(b * NH + h);
                if (part == 0)      qws[(bh * LSEQ + l) * HD + d] = f2bf(v * SCALING);
                else if (part == 1) kws[(bh * LSEQ + l) * HD + d] = f2bf(v);
                else                vws[(bh * HD + d) * LSEQ + l] = f2bf(v);   // transposed
            }
        }
    }
}

// ================= Kernel 2: flash attention =================
// 1-D grid of 1024 blocks; XCD-swizzled so the 16 q-tiles of one (b,h)
// share an XCD (K/V stay L2-resident). Each wave owns 16 Q rows.
// Bias tile is register-prefetched one k-tile ahead.
__global__ __launch_bounds__(256, 3) void attn_kernel(
    const short* __restrict__ qws, const short* __restrict__ kws,
    const short* __restrict__ vws, const float* __restrict__ bias,
    const unsigned char* __restrict__ mask, short* __restrict__ att)
{
    __shared__ short Ks[128 * 72];    // [key][d], stride 72 shorts (144 B)
    __shared__ short Vs[64 * 136];    // [d][key], stride 136 shorts (272 B)
    __shared__ short PQ[4 * 2176];    // per-wave P (16x136); doubles as Q stage at start
    // LDS total: 18432 + 17408 + 17408 = 53248 B -> 3 blocks/CU

    const int flat = blockIdx.x;      // 0..1023
    const int xcd = flat & 7, ii = flat >> 3;
    const int bh = xcd * 8 + (ii >> 4);   // 16 consecutive-per-XCD blocks share bh
    const int qt = ii & 15;
    const int b = bh >> 4, h = bh & 15;
    const int tid = threadIdx.x, wave = tid >> 6, lane = tid & 63;
    const int quad = lane >> 4, l16 = lane & 15;

    const short* Qg = qws + (size_t)bh * LSEQ * HD + (size_t)qt * 64 * HD;
    const short* Kg = kws + (size_t)bh * LSEQ * HD;
    const short* Vg = vws + (size_t)bh * HD * LSEQ;   // [d][l]
    const float* Bg = bias + (size_t)bh * LSEQ * LSEQ;
    const unsigned char* Mg = mask + (size_t)b * LSEQ;

    // ---- stage Q tile (64x64) into PQ with stride 72, read frags, then reuse
    #pragma unroll
    for (int i = 0; i < 2; i++) {
        int c = i * 256 + tid;
        int row = c >> 3, col8 = c & 7;
        *(int4*)((char*)PQ + row * 144 + col8 * 16) =
            *(const int4*)((const char*)Qg + row * 128 + col8 * 16);
    }
    __syncthreads();
    short8 qf[2];
    #pragma unroll
    for (int ks = 0; ks < 2; ks++)
        qf[ks] = *(const short8*)((const char*)PQ + (wave * 16 + l16) * 144 + ks * 64 + quad * 16);

    float m_r[4], l_r[4];
    f32x4 o[4] = {};
    #pragma unroll
    for (int r = 0; r < 4; r++) { m_r[r] = -INFINITY; l_r[r] = 0.0f; }

    const int qrow_g = qt * 64 + wave * 16 + quad * 4;   // + r

    // ---- prefetch bias + mask for k-tile 0 into registers
    float bv[8][4];
    float mkf[8];
    #pragma unroll
    for (int ni = 0; ni < 8; ni++) {
        int col = ni * 16 + l16;
        mkf[ni] = Mg[col] ? -INFINITY : 0.0f;
        #pragma unroll
        for (int r = 0; r < 4; r++)
            bv[ni][r] = Bg[(size_t)(qrow_g + r) * LSEQ + col];
    }

    short* Pw = PQ + wave * 2176;     // this wave's 16x136 P buffer

    for (int kt0 = 0; kt0 < LSEQ; kt0 += 128) {
        __syncthreads();   // prior-iteration Ks/Vs readers done; also fences PQ->Pw reuse
        // stage K tile (128x64, natural layout): 1024 int4 chunks, 4/thread
        #pragma unroll
        for (int i = 0; i < 4; i++) {
            int c = i * 256 + tid;
            int row = c >> 3, col8 = c & 7;
            *(int4*)((char*)Ks + row * 144 + col8 * 16) =
                *(const int4*)((const char*)Kg + (size_t)(kt0 + row) * 128 + col8 * 16);
        }
        // stage V tile (already [d][key] in global): 1024 int4 chunks, 4/thread
        #pragma unroll
        for (int i = 0; i < 4; i++) {
            int c = i * 256 + tid;
            int row = c >> 4, col16 = c & 15;   // row = d, 16 chunks per 256B row
            *(int4*)((char*)Vs + row * 272 + col16 * 16) =
                *(const int4*)((const char*)Vg + (size_t)row * 2048 + kt0 * 2 + col16 * 16);
        }
        __syncthreads();

        // S = Q K^T : 16 rows x 128 cols per wave
        f32x4 s[8] = {};
        #pragma unroll
        for (int ni = 0; ni < 8; ni++) {
            #pragma unroll
            for (int ks = 0; ks < 2; ks++) {
                short8 kf = *(const short8*)((const char*)Ks + (ni * 16 + l16) * 144 + ks * 64 + quad * 16);
                s[ni] = __builtin_amdgcn_mfma_f32_16x16x32_bf16(qf[ks], kf, s[ni], 0, 0, 0);
            }
        }

        // consume prefetched bias + mask
        #pragma unroll
        for (int ni = 0; ni < 8; ni++) {
            #pragma unroll
            for (int r = 0; r < 4; r++)
                s[ni][r] = s[ni][r] + bv[ni][r] + mkf[ni];
        }
        // issue next tile's bias/mask prefetch (hidden behind softmax + PV MFMA)
        if (kt0 + 128 < LSEQ) {
            int nk = kt0 + 128;
            #pragma unroll
            for (int ni = 0; ni < 8; ni++) {
                int col = nk + ni * 16 + l16;
                mkf[ni] = Mg[col] ? -INFINITY : 0.0f;
                #pragma unroll
                for (int r = 0; r < 4; r++)
                    bv[ni][r] = Bg[(size_t)(qrow_g + r) * LSEQ + col];
            }
        }

        // online softmax per row
        #pragma unroll
        for (int r = 0; r < 4; r++) {
            float mx = s[0][r];
            #pragma unroll
            for (int ni = 1; ni < 8; ni++) mx = fmaxf(mx, s[ni][r]);
            #pragma unroll
            for (int off = 1; off < 16; off <<= 1)
                mx = fmaxf(mx, __shfl_xor(mx, off, 64));
            float mnew = fmaxf(m_r[r], mx);
            float alpha = (m_r[r] == -INFINITY) ? 0.0f : __expf(m_r[r] - mnew);
            m_r[r] = mnew;
            float sum = 0.0f;
            #pragma unroll
            for (int ni = 0; ni < 8; ni++) {
                float p = __expf(s[ni][r] - mnew);
                s[ni][r] = p;
                sum += p;
            }
            #pragma unroll
            for (int off = 1; off < 16; off <<= 1)
                sum += __shfl_xor(sum, off, 64);
            l_r[r] = l_r[r] * alpha + sum;
            #pragma unroll
            for (int ni2 = 0; ni2 < 4; ni2++) o[ni2][r] *= alpha;
            // write P row to wave-private LDS (A-layout source); no barrier needed
            #pragma unroll
            for (int ni = 0; ni < 8; ni++)
                Pw[(quad * 4 + r) * 136 + ni * 16 + l16] = f2bf(s[ni][r]);
        }

        // O += P V  (A-frag from Pw, B-frag from Vs)
        #pragma unroll
        for (int ks = 0; ks < 4; ks++) {
            short8 pf = *(const short8*)((const char*)Pw + l16 * 272 + ks * 64 + quad * 16);
            #pragma unroll
            for (int ni2 = 0; ni2 < 4; ni2++) {
                short8 vf = *(const short8*)((const char*)Vs + (ni2 * 16 + l16) * 272 + ks * 64 + quad * 16);
                o[ni2] = __builtin_amdgcn_mfma_f32_16x16x32_bf16(pf, vf, o[ni2], 0, 0, 0);
            }
        }
    }

    // normalize + write att[b][l][h*64+d] (bf16 ws, feeds out_gemm)
    #pragma unroll
    for (int r = 0; r < 4; r++) {
        float inv = 1.0f / l_r[r];
        int lq = qt * 64 + wave * 16 + quad * 4 + r;
        #pragma unroll
        for (int ni2 = 0; ni2 < 4; ni2++) {
            int d = ni2 * 16 + l16;
            att[((size_t)(b * LSEQ + lq)) * EMB + h * HD + d] = f2bf(o[ni2][r] * inv);
        }
    }
}

// ================= Kernel 3: output projection =================
// out[n][f] = sum_e att[n][e]*Wo[f][e] + bo[f].  M=4096, N=1024, K=1024. f32 out.
__global__ __launch_bounds__(256) void out_gemm(
    const short* __restrict__ Xa, const short* __restrict__ Wo,
    const float* __restrict__ bo, float* __restrict__ out)
{
    __shared__ short As[128 * 32];
    __shared__ short Bs[128 * 32];
    const int tid = threadIdx.x;
    const int wave = tid >> 6, lane = tid & 63;
    const int quad = lane >> 4, l16 = lane & 15;
    const int m0 = blockIdx.y * 128, n0 = blockIdx.x * 128;
    const int wm = (wave >> 1) * 64, wn = (wave & 1) * 64;

    f32x4 acc[4][4] = {};

    const int srow = wave * 16 + (lane >> 2);
    const int scol = (lane & 3) * 16;
    const char* gA = (const char*)Xa + (size_t)(m0 + srow) * 2048 + scol;
    const char* gB = (const char*)Wo + (size_t)(n0 + srow) * 2048 + scol;
    char* lA = (char*)As + wave * 1024 + lane * 16;
    char* lB = (char*)Bs + wave * 1024 + lane * 16;

    for (int kt = 0; kt < 1024; kt += 32) {
        __syncthreads();
        const char* ga = gA + kt * 2;
        const char* gb = gB + kt * 2;
        glds16(ga, lA);
        glds16(ga + (size_t)64 * 2048, lA + 4096);
        glds16(gb, lB);
        glds16(gb + (size_t)64 * 2048, lB + 4096);
        __syncthreads();

        short8 af[4], bf[4];
        #pragma unroll
        for (int i = 0; i < 4; i++)
            af[i] = *(const short8*)((const char*)As + (wm + i * 16 + l16) * 64 + quad * 16);
        #pragma unroll
        for (int j = 0; j < 4; j++)
            bf[j] = *(const short8*)((const char*)Bs + (wn + j * 16 + l16) * 64 + quad * 16);
        #pragma unroll
        for (int i = 0; i < 4; i++)
            #pragma unroll
            for (int j = 0; j < 4; j++)
                acc[i][j] = __builtin_amdgcn_mfma_f32_16x16x32_bf16(af[i], bf[j], acc[i][j], 0, 0, 0);
    }

    #pragma unroll
    for (int i = 0; i < 4; i++) {
        #pragma unroll
        for (int j = 0; j < 4; j++) {
            #pragma unroll
            for (int r = 0; r < 4; r++) {
                int gm = m0 + wm + i * 16 + quad * 4 + r;
                int gn = n0 + wn + j * 16 + l16;
                out[(size_t)gm * EMB + gn] = acc[i][j][r] + bo[gn];
            }
        }
    }
}

// ================= launch =================
extern "C" void kernel_launch(void* const* d_in, const int* in_sizes, int n_in,
                              void* d_out, int out_size, void* d_ws, size_t ws_size,
                              hipStream_t stream) {
    const float* query = (const float*)d_in[0];          // (4,1024,1024) f32
    const unsigned char* mask = (const unsigned char*)d_in[1]; // (4,1024) bool
    const float* bias = (const float*)d_in[2];           // (64,1024,1024) f32
    const float* Wqkv = (const float*)d_in[3];           // (3072,1024) f32
    const float* bqkv = (const float*)d_in[4];           // (3072,) f32
    const float* Wo   = (const float*)d_in[5];           // (1024,1024) f32
    const float* bo   = (const float*)d_in[6];           // (1024,) f32
    float* out = (float*)d_out;                          // (4,1024,1024) f32

    // workspace layout (bf16 shorts)
    short* Xb  = (short*)d_ws;                       // 4096*1024
    short* Wb  = Xb  + (size_t)4096 * 1024;          // 3072*1024
    short* Wob = Wb  + (size_t)3072 * 1024;          // 1024*1024
    short* qws = Wob + (size_t)1024 * 1024;          // 64*1024*64  [bh][l][d]
    short* kws = qws + (size_t)64 * 1024 * 64;       //             [bh][l][d]
    short* vws = kws + (size_t)64 * 1024 * 64;       //             [bh][d][l]
    short* att = vws + (size_t)64 * 1024 * 64;       // 4096*1024

    cvt_bf16<<<dim3(4096 * 1024 / 8 / 256), 256, 0, stream>>>(query, Xb, 4096 * 1024);
    cvt_bf16<<<dim3(3072 * 1024 / 8 / 256), 256, 0, stream>>>(Wqkv, Wb, 3072 * 1024);
    cvt_bf16<<<dim3(1024 * 1024 / 8 / 256), 256, 0, stream>>>(Wo, Wob, 1024 * 1024);

    qkv_gemm<<<dim3(24, 32), 256, 0, stream>>>(Xb, Wb, bqkv, qws, kws, vws);
    attn_kernel<<<dim3(1024), 256, 0, stream>>>(qws, kws, vws, bias, mask, att);
    out_gemm<<<dim3(8, 32), 256, 0, stream>>>(att, Wob, bo, out);
}

// Round 4
// 492.398 us; speedup vs baseline: 1.5031x; 1.5031x over previous
//
#include <hip/hip_runtime.h>
#include <math.h>

// ---------------- constants ----------------
#define EMB   1024
#define NH    16
#define HD    64
#define BATCH 4
#define LSEQ  1024
#define NTOK  (BATCH*LSEQ)          // 4096
#define SCALING 0.39528470752104744f // (64*0.1)^-0.5

typedef __attribute__((ext_vector_type(8))) short short8;   // 8 bf16 = 4 VGPRs
typedef __attribute__((ext_vector_type(4))) float f32x4;

__device__ __forceinline__ float bf2f(short s) {
    union { float f; unsigned u; } x; x.u = ((unsigned)(unsigned short)s) << 16; return x.f;
}
__device__ __forceinline__ short f2bf(float f) {
    union { float f; unsigned u; } x; x.f = f;
    unsigned r = x.u + 0x7fff + ((x.u >> 16) & 1);
    return (short)(r >> 16);
}

__device__ __forceinline__ void glds16(const void* g, void* l) {
    __builtin_amdgcn_global_load_lds(
        (const __attribute__((address_space(1))) void*)g,
        (__attribute__((address_space(3))) void*)l, 16, 0, 0);
}

// ================= Kernel 0: f32 -> bf16 conversion =================
__global__ __launch_bounds__(256) void cvt_bf16(
    const float* __restrict__ in, short* __restrict__ out, int n)
{
    int i = (blockIdx.x * 256 + threadIdx.x) * 8;
    if (i >= n) return;
    float4 a = *(const float4*)(in + i);
    float4 b = *(const float4*)(in + i + 4);
    short8 o;
    o[0] = f2bf(a.x); o[1] = f2bf(a.y); o[2] = f2bf(a.z); o[3] = f2bf(a.w);
    o[4] = f2bf(b.x); o[5] = f2bf(b.y); o[6] = f2bf(b.z); o[7] = f2bf(b.w);
    *(short8*)(out + i) = o;
}

// ================= Kernel 1: QKV GEMM =================
// Q,K,V all scatter NATURAL [bh][l][d] (consecutive lanes -> consecutive d:
// contiguous 32B segments; the round-3 V-transposed scatter caused ~30x
// write amplification). V is transposed by vtrans afterwards.
__global__ __launch_bounds__(256) void qkv_gemm(
    const short* __restrict__ X, const short* __restrict__ W,
    const float* __restrict__ bqkv,
    short* __restrict__ qws, short* __restrict__ kws, short* __restrict__ vws)
{
    __shared__ short As[128 * 32];
    __shared__ short Bs[128 * 32];
    const int tid = threadIdx.x;
    const int wave = tid >> 6, lane = tid & 63;
    const int quad = lane >> 4, l16 = lane & 15;
    const int m0 = blockIdx.y * 128, n0 = blockIdx.x * 128;
    const int wm = (wave >> 1) * 64, wn = (wave & 1) * 64;

    f32x4 acc[4][4] = {};

    const int srow = wave * 16 + (lane >> 2);
    const int scol = (lane & 3) * 16;
    const char* gA = (const char*)X + (size_t)(m0 + srow) * 2048 + scol;
    const char* gB = (const char*)W + (size_t)(n0 + srow) * 2048 + scol;
    char* lA = (char*)As + wave * 1024 + lane * 16;
    char* lB = (char*)Bs + wave * 1024 + lane * 16;

    for (int kt = 0; kt < 1024; kt += 32) {
        __syncthreads();
        const char* ga = gA + kt * 2;
        const char* gb = gB + kt * 2;
        glds16(ga, lA);
        glds16(ga + (size_t)64 * 2048, lA + 4096);
        glds16(gb, lB);
        glds16(gb + (size_t)64 * 2048, lB + 4096);
        __syncthreads();

        short8 af[4], bf[4];
        #pragma unroll
        for (int i = 0; i < 4; i++)
            af[i] = *(const short8*)((const char*)As + (wm + i * 16 + l16) * 64 + quad * 16);
        #pragma unroll
        for (int j = 0; j < 4; j++)
            bf[j] = *(const short8*)((const char*)Bs + (wn + j * 16 + l16) * 64 + quad * 16);
        #pragma unroll
        for (int i = 0; i < 4; i++)
            #pragma unroll
            for (int j = 0; j < 4; j++)
                acc[i][j] = __builtin_amdgcn_mfma_f32_16x16x32_bf16(af[i], bf[j], acc[i][j], 0, 0, 0);
    }

    #pragma unroll
    for (int i = 0; i < 4; i++) {
        #pragma unroll
        for (int j = 0; j < 4; j++) {
            #pragma unroll
            for (int r = 0; r < 4; r++) {
                int gm = m0 + wm + i * 16 + quad * 4 + r;   // token
                int gn = n0 + wn + j * 16 + l16;            // feature [0,3072)
                float v = acc[i][j][r] + bqkv[gn];
                int part = gn >> 10;
                int cc = gn & 1023;
                int h = cc >> 6, d = cc & 63;
                int b = gm >> 10, l = gm & 1023;
                size_t dst = (((size_t)(b * NH + h)) * LSEQ + l) * HD + d;
                if (part == 0)      qws[dst] = f2bf(v * SCALING);
                else if (part == 1) kws[dst] = f2bf(v);
                else                vws[dst] = f2bf(v);
            }
        }
    }
}

// ================= Kernel 1b: V transpose =================
// [bh][l][d] -> [bh][d][l], 64x64 tiles through LDS.
__global__ __launch_bounds__(256) void vtrans(
    const short* __restrict__ vin, short* __restrict__ vout)
{
    __shared__ short T[64 * 66];
    const int bh = blockIdx.y, lt = blockIdx.x;
    const int tid = threadIdx.x;
    const short* src = vin + ((size_t)bh * LSEQ + lt * 64) * HD;
    #pragma unroll
    for (int i = 0; i < 2; i++) {
        int c = i * 256 + tid;
        int row = c >> 3, col8 = c & 7;
        *(short8*)&T[row * 66 + col8 * 8] = *(const short8*)(src + row * 64 + col8 * 8);
    }
    __syncthreads();
    short* dst = vout + (size_t)bh * HD * LSEQ + lt * 64;
    #pragma unroll
    for (int i = 0; i < 2; i++) {
        int c = i * 256 + tid;
        int d = c >> 3, lc = (c & 7) * 8;
        short8 v;
        #pragma unroll
        for (int j = 0; j < 8; j++) v[j] = T[(lc + j) * 66 + d];
        *(short8*)(dst + (size_t)d * LSEQ + lc) = v;
    }
}

// ================= Kernel 2: flash attention =================
// All streaming (Q,K,V,bias) via global_load_lds width-16 (deep DMA queue,
// no VGPR round trip). glds16 forbids LDS padding -> K/V use XOR chunk
// swizzle (chunk ^ (row&7)) for conflict-free b128 fragment reads.
// Bias tile (64x128 f32, 32KB) staged per-wave-private; P overlays it after
// consumption. LDS = 16+16+32 KB = 64 KB -> 2 blocks/CU.
__global__ __launch_bounds__(256) void attn_kernel(
    const short* __restrict__ qws, const short* __restrict__ kws,
    const short* __restrict__ vt, const float* __restrict__ bias,
    const unsigned char* __restrict__ mask, short* __restrict__ att)
{
    __shared__ short Ks[128 * 64];     // [key][d-chunk swizzled], stride 128 B
    __shared__ short Vs[64 * 128];     // [d][key-chunk swizzled], stride 256 B
    __shared__ float BiasP[4 * 2048];  // per-wave 8 KB bias tile; P overlays

    const int flat = blockIdx.x;       // 0..1023, XCD-swizzled
    const int xcd = flat & 7, ii = flat >> 3;
    const int bh = xcd * 8 + (ii >> 4);
    const int qt = ii & 15;
    const int b = bh >> 4, h = bh & 15;
    const int tid = threadIdx.x, wave = tid >> 6, lane = tid & 63;
    const int quad = lane >> 4, l16 = lane & 15;
    const int h7 = l16 & 7;

    const short* Qg = qws + (size_t)bh * LSEQ * HD + (size_t)qt * 64 * HD;
    const short* Kg = kws + (size_t)bh * LSEQ * HD;
    const short* Vg = vt  + (size_t)bh * HD * LSEQ;   // [d][l]
    const float* Bg = bias + (size_t)bh * LSEQ * LSEQ;
    const unsigned char* Mg = mask + (size_t)b * LSEQ;

    // ---- stage Q (64 rows x 128 B) into Ks via swizzled glds16
    {
        int rl = lane >> 3, c = lane & 7;
        #pragma unroll
        for (int i = 0; i < 2; i++) {
            int row = wave * 16 + i * 8 + rl;      // row&7 == rl
            glds16((const char*)Qg + (size_t)row * 128 + ((c ^ rl) * 16),
                   (char*)Ks + (wave * 16 + i * 8) * 128);
        }
    }
    __syncthreads();
    short8 qf[2];
    {
        int row = wave * 16 + l16;
        #pragma unroll
        for (int ks = 0; ks < 2; ks++)
            qf[ks] = *(const short8*)((const char*)Ks + row * 128 + (((ks * 4 + quad) ^ h7) * 16));
    }

    float m_r[4], l_r[4];
    f32x4 o[4] = {};
    #pragma unroll
    for (int r = 0; r < 4; r++) { m_r[r] = -INFINITY; l_r[r] = 0.0f; }

    short* Pw = (short*)(BiasP + wave * 2048);   // 16x136 shorts (4352 B <= 8192)

    for (int kt0 = 0; kt0 < LSEQ; kt0 += 128) {
        __syncthreads();   // prior readers of Ks/Vs/BiasP done (also covers qf reads)

        // K tile: 128 rows x 128 B, swizzled
        {
            int rl = lane >> 3, c = lane & 7;
            #pragma unroll
            for (int i = 0; i < 4; i++) {
                int row = wave * 32 + i * 8 + rl;          // row&7 == rl
                glds16((const char*)Kg + (size_t)(kt0 + row) * 128 + ((c ^ rl) * 16),
                       (char*)Ks + (wave * 32 + i * 8) * 128);
            }
        }
        // V tile: 64 rows(d) x 256 B, swizzled
        {
            int rl = lane >> 4, c = lane & 15;
            #pragma unroll
            for (int i = 0; i < 4; i++) {
                int row = wave * 16 + i * 4 + rl;          // row&7 == (i*4+rl)&7
                glds16((const char*)Vg + (size_t)row * 2048 + (size_t)kt0 * 2 + ((c ^ (row & 7)) * 16),
                       (char*)Vs + (wave * 16 + i * 4) * 256);
            }
        }
        // Bias tile: wave-private 16 rows x 512 B (f32), natural layout
        {
            int r2 = lane >> 5, c = lane & 31;
            #pragma unroll
            for (int i = 0; i < 8; i++) {
                int row = qt * 64 + wave * 16 + 2 * i + r2;
                glds16((const char*)Bg + (size_t)row * 4096 + (size_t)kt0 * 4 + c * 16,
                       (char*)BiasP + wave * 8192 + i * 1024);
            }
        }
        __syncthreads();   // drains vmcnt: everything staged

        // S = Q K^T : 16 rows x 128 cols per wave
        f32x4 s[8] = {};
        #pragma unroll
        for (int ni = 0; ni < 8; ni++) {
            int row = ni * 16 + l16;
            #pragma unroll
            for (int ks = 0; ks < 2; ks++) {
                short8 kf = *(const short8*)((const char*)Ks + row * 128 + (((ks * 4 + quad) ^ h7) * 16));
                s[ni] = __builtin_amdgcn_mfma_f32_16x16x32_bf16(qf[ks], kf, s[ni], 0, 0, 0);
            }
        }

        // bias (from per-wave LDS) + mask
        #pragma unroll
        for (int ni = 0; ni < 8; ni++) {
            float mk = Mg[kt0 + ni * 16 + l16] ? -INFINITY : 0.0f;
            #pragma unroll
            for (int r = 0; r < 4; r++)
                s[ni][r] += BiasP[wave * 2048 + (quad * 4 + r) * 128 + ni * 16 + l16] + mk;
        }
        __asm volatile("" ::: "memory");   // order bias f32 reads before P short writes

        // online softmax per row
        #pragma unroll
        for (int r = 0; r < 4; r++) {
            float mx = s[0][r];
            #pragma unroll
            for (int ni = 1; ni < 8; ni++) mx = fmaxf(mx, s[ni][r]);
            #pragma unroll
            for (int off = 1; off < 16; off <<= 1)
                mx = fmaxf(mx, __shfl_xor(mx, off, 64));
            float mnew = fmaxf(m_r[r], mx);
            float alpha = (m_r[r] == -INFINITY) ? 0.0f : __expf(m_r[r] - mnew);
            m_r[r] = mnew;
            float sum = 0.0f;
            #pragma unroll
            for (int ni = 0; ni < 8; ni++) {
                float p = __expf(s[ni][r] - mnew);
                s[ni][r] = p;
                sum += p;
            }
            #pragma unroll
            for (int off = 1; off < 16; off <<= 1)
                sum += __shfl_xor(sum, off, 64);
            l_r[r] = l_r[r] * alpha + sum;
            #pragma unroll
            for (int ni2 = 0; ni2 < 4; ni2++) o[ni2][r] *= alpha;
            // write P row (wave-private region; overlays consumed bias)
            #pragma unroll
            for (int ni = 0; ni < 8; ni++)
                Pw[(quad * 4 + r) * 136 + ni * 16 + l16] = f2bf(s[ni][r]);
        }

        // O += P V
        #pragma unroll
        for (int ks = 0; ks < 4; ks++) {
            short8 pf = *(const short8*)((const char*)Pw + l16 * 272 + ks * 64 + quad * 16);
            #pragma unroll
            for (int ni2 = 0; ni2 < 4; ni2++) {
                int row = ni2 * 16 + l16;
                short8 vf = *(const short8*)((const char*)Vs + row * 256 + (((ks * 4 + quad) ^ h7) * 16));
                o[ni2] = __builtin_amdgcn_mfma_f32_16x16x32_bf16(pf, vf, o[ni2], 0, 0, 0);
            }
        }
    }

    // normalize + write att[b][l][h*64+d]
    #pragma unroll
    for (int r = 0; r < 4; r++) {
        float inv = 1.0f / l_r[r];
        int lq = qt * 64 + wave * 16 + quad * 4 + r;
        #pragma unroll
        for (int ni2 = 0; ni2 < 4; ni2++) {
            int d = ni2 * 16 + l16;
            att[((size_t)(b * LSEQ + lq)) * EMB + h * HD + d] = f2bf(o[ni2][r] * inv);
        }
    }
}

// ================= Kernel 3: output projection =================
__global__ __launch_bounds__(256) void out_gemm(
    const short* __restrict__ Xa, const short* __restrict__ Wo,
    const float* __restrict__ bo, float* __restrict__ out)
{
    __shared__ short As[128 * 32];
    __shared__ short Bs[128 * 32];
    const int tid = threadIdx.x;
    const int wave = tid >> 6, lane = tid & 63;
    const int quad = lane >> 4, l16 = lane & 15;
    const int m0 = blockIdx.y * 128, n0 = blockIdx.x * 128;
    const int wm = (wave >> 1) * 64, wn = (wave & 1) * 64;

    f32x4 acc[4][4] = {};

    const int srow = wave * 16 + (lane >> 2);
    const int scol = (lane & 3) * 16;
    const char* gA = (const char*)Xa + (size_t)(m0 + srow) * 2048 + scol;
    const char* gB = (const char*)Wo + (size_t)(n0 + srow) * 2048 + scol;
    char* lA = (char*)As + wave * 1024 + lane * 16;
    char* lB = (char*)Bs + wave * 1024 + lane * 16;

    for (int kt = 0; kt < 1024; kt += 32) {
        __syncthreads();
        const char* ga = gA + kt * 2;
        const char* gb = gB + kt * 2;
        glds16(ga, lA);
        glds16(ga + (size_t)64 * 2048, lA + 4096);
        glds16(gb, lB);
        glds16(gb + (size_t)64 * 2048, lB + 4096);
        __syncthreads();

        short8 af[4], bf[4];
        #pragma unroll
        for (int i = 0; i < 4; i++)
            af[i] = *(const short8*)((const char*)As + (wm + i * 16 + l16) * 64 + quad * 16);
        #pragma unroll
        for (int j = 0; j < 4; j++)
            bf[j] = *(const short8*)((const char*)Bs + (wn + j * 16 + l16) * 64 + quad * 16);
        #pragma unroll
        for (int i = 0; i < 4; i++)
            #pragma unroll
            for (int j = 0; j < 4; j++)
                acc[i][j] = __builtin_amdgcn_mfma_f32_16x16x32_bf16(af[i], bf[j], acc[i][j], 0, 0, 0);
    }

    #pragma unroll
    for (int i = 0; i < 4; i++) {
        #pragma unroll
        for (int j = 0; j < 4; j++) {
            #pragma unroll
            for (int r = 0; r < 4; r++) {
                int gm = m0 + wm + i * 16 + quad * 4 + r;
                int gn = n0 + wn + j * 16 + l16;
                out[(size_t)gm * EMB + gn] = acc[i][j][r] + bo[gn];
            }
        }
    }
}

// ================= launch =================
extern "C" void kernel_launch(void* const* d_in, const int* in_sizes, int n_in,
                              void* d_out, int out_size, void* d_ws, size_t ws_size,
                              hipStream_t stream) {
    const float* query = (const float*)d_in[0];
    const unsigned char* mask = (const unsigned char*)d_in[1];
    const float* bias = (const float*)d_in[2];
    const float* Wqkv = (const float*)d_in[3];
    const float* bqkv = (const float*)d_in[4];
    const float* Wo   = (const float*)d_in[5];
    const float* bo   = (const float*)d_in[6];
    float* out = (float*)d_out;

    // workspace (bf16 shorts). Xb doubles as V^T storage after qkv_gemm.
    short* Xb  = (short*)d_ws;                       // 4096*1024 (X, then V^T)
    short* Wb  = Xb  + (size_t)4096 * 1024;          // 3072*1024
    short* Wob = Wb  + (size_t)3072 * 1024;          // 1024*1024
    short* qws = Wob + (size_t)1024 * 1024;          // [bh][l][d]
    short* kws = qws + (size_t)64 * 1024 * 64;       // [bh][l][d]
    short* vws = kws + (size_t)64 * 1024 * 64;       // [bh][l][d]
    short* att = vws + (size_t)64 * 1024 * 64;       // 4096*1024

    cvt_bf16<<<dim3(4096 * 1024 / 8 / 256), 256, 0, stream>>>(query, Xb, 4096 * 1024);
    cvt_bf16<<<dim3(3072 * 1024 / 8 / 256), 256, 0, stream>>>(Wqkv, Wb, 3072 * 1024);
    cvt_bf16<<<dim3(1024 * 1024 / 8 / 256), 256, 0, stream>>>(Wo, Wob, 1024 * 1024);

    qkv_gemm<<<dim3(24, 32), 256, 0, stream>>>(Xb, Wb, bqkv, qws, kws, vws);
    vtrans<<<dim3(16, 64), 256, 0, stream>>>(vws, Xb);          // Xb := V^T
    attn_kernel<<<dim3(1024), 256, 0, stream>>>(qws, kws, Xb, bias, mask, att);
    out_gemm<<<dim3(8, 32), 256, 0, stream>>>(att, Wob, bo, out);
}